// Round 6
// baseline (397.437 us; speedup 1.0000x reference)
//
#include <hip/hip_runtime.h>
#include <hip/hip_bf16.h>
#include <cstdint>

#define EMB 1024
#define HEADS 16
#define HD 64
#define BATCH 4
#define SEQ 2048
#define BT (BATCH*SEQ)                 // 8192 tokens
#define LNEPS 1e-5f
#define QK_SCALE 0.17677669529663687f  // 1024^-0.25
#define LOG2E 1.4426950408889634f

typedef __bf16 bf16;
typedef __bf16 bf16x8 __attribute__((ext_vector_type(8)));
typedef __bf16 bf16x4 __attribute__((ext_vector_type(4)));
typedef float  f32x4  __attribute__((ext_vector_type(4)));
typedef short  s16x4  __attribute__((ext_vector_type(4)));

typedef const __attribute__((address_space(1))) void* gas_ptr;
typedef __attribute__((address_space(3))) void*       las_ptr;

__device__ __forceinline__ void gld_lds16(const void* g, void* l) {
  __builtin_amdgcn_global_load_lds((gas_ptr)g, (las_ptr)l, 16, 0, 0);
}

// PV matmul: 16x16x16 bf16 MFMA (C-layout of S^T == B-layout of this shape).
// gfx950 keeps the gfx90a-era builtin name (v4i16 operands).
__device__ __forceinline__ f32x4 mfma_pv(bf16x4 a, bf16x4 b, f32x4 c) {
  return __builtin_amdgcn_mfma_f32_16x16x16bf16_1k(
      __builtin_bit_cast(s16x4, a), __builtin_bit_cast(s16x4, b), c, 0, 0, 0);
}

// ---------------- fp32 -> bf16 conversion ----------------
__global__ void cvt_f32_bf16(const float* __restrict__ src, bf16* __restrict__ dst, int n4) {
  int i = blockIdx.x * blockDim.x + threadIdx.x;
  if (i >= n4) return;
  float4 f = reinterpret_cast<const float4*>(src)[i];
  bf16x4 o = { (bf16)f.x, (bf16)f.y, (bf16)f.z, (bf16)f.w };
  reinterpret_cast<bf16x4*>(dst)[i] = o;
}

// 4 weight matrices (1024x1024 each) -> contiguous bf16 [4*1024][1024]
__global__ void cvt_w4(const float* __restrict__ w0, const float* __restrict__ w1,
                       const float* __restrict__ w2, const float* __restrict__ w3,
                       bf16* __restrict__ dst) {
  int i = blockIdx.x * blockDim.x + threadIdx.x;   // over 4*262144 float4s
  int sel = i >> 18;
  int j = i & 262143;
  const float* s = (sel == 0) ? w0 : (sel == 1) ? w1 : (sel == 2) ? w2 : w3;
  float4 f = reinterpret_cast<const float4*>(s)[j];
  bf16x4 o = { (bf16)f.x, (bf16)f.y, (bf16)f.z, (bf16)f.w };
  reinterpret_cast<bf16x4*>(dst)[i] = o;
}

// ---------------- m97-style GEMM: C[M][N] = A[M][K] * B[N][K]^T ----------------
template<int OUTF32>
__global__ __launch_bounds__(256, 2) void gemm_bt(
    const bf16* __restrict__ A, const bf16* __restrict__ Bm,
    bf16* __restrict__ Cb, float* __restrict__ Cf, const float* __restrict__ bias,
    int M, int N, int K)
{
  __shared__ __align__(16) bf16 As[128 * 32];
  __shared__ __align__(16) bf16 Bs[128 * 32];

  const int t    = threadIdx.x;
  const int lane = t & 63;
  const int wave = t >> 6;
  const int q    = lane >> 4;
  const int ln   = lane & 15;
  const int m0   = blockIdx.y * 128;
  const int n0   = blockIdx.x * 128;
  const int wm   = (wave >> 1) * 64;
  const int wn   = (wave & 1) * 64;

  const int r0 = t >> 2;
  const int c0 = (t & 3) << 3;

  f32x4 zero4 = {0.f, 0.f, 0.f, 0.f};
  f32x4 acc[4][4];
#pragma unroll
  for (int i = 0; i < 4; i++)
#pragma unroll
    for (int j = 0; j < 4; j++) acc[i][j] = zero4;

  for (int k0 = 0; k0 < K; k0 += 32) {
    __syncthreads();
    const bf16* ga = A  + (size_t)(m0 + r0) * K + k0 + c0;
    const bf16* gb = Bm + (size_t)(n0 + r0) * K + k0 + c0;
    gld_lds16(ga,                  &As[t * 8]);
    gld_lds16(ga + (size_t)64 * K, &As[t * 8 + 2048]);
    gld_lds16(gb,                  &Bs[t * 8]);
    gld_lds16(gb + (size_t)64 * K, &Bs[t * 8 + 2048]);
    __syncthreads();

    bf16x8 af[4], bfr[4];
#pragma unroll
    for (int mi = 0; mi < 4; mi++)
      af[mi] = *reinterpret_cast<const bf16x8*>(&As[(wm + mi * 16 + ln) * 32 + q * 8]);
#pragma unroll
    for (int ni = 0; ni < 4; ni++)
      bfr[ni] = *reinterpret_cast<const bf16x8*>(&Bs[(wn + ni * 16 + ln) * 32 + q * 8]);
#pragma unroll
    for (int mi = 0; mi < 4; mi++)
#pragma unroll
      for (int ni = 0; ni < 4; ni++)
        acc[mi][ni] = __builtin_amdgcn_mfma_f32_16x16x32_bf16(af[mi], bfr[ni], acc[mi][ni], 0, 0, 0);
  }

#pragma unroll
  for (int mi = 0; mi < 4; mi++) {
#pragma unroll
    for (int ni = 0; ni < 4; ni++) {
#pragma unroll
      for (int r = 0; r < 4; r++) {
        int row = m0 + wm + mi * 16 + q * 4 + r;
        int col = n0 + wn + ni * 16 + ln;
        float v = acc[mi][ni][r];
        if (OUTF32) Cf[(size_t)row * N + col] = v + bias[col];
        else        Cb[(size_t)row * N + col] = (bf16)v;
      }
    }
  }
}

// ---------------- per-head LayerNorm for K and Q in one pass ----------------
// kqv: [8192][3072]; K at col 0, Q at col 1024. Outputs [bh][t][64].
// kscale includes log2(e) so attention can use exp2 directly.
__global__ void ln_kq(const bf16* __restrict__ kqv,
                      bf16* __restrict__ kn, bf16* __restrict__ qn,
                      const float* __restrict__ kg, const float* __restrict__ kb,
                      const float* __restrict__ qg, const float* __restrict__ qb,
                      float kscale, float qscale)
{
  int wave = threadIdx.x >> 6, lane = threadIdx.x & 63;
  int row = blockIdx.x * 4 + wave;        // row = t*16 + h
  int tok = row >> 4, h = row & 15;
  size_t base = (size_t)tok * (3 * EMB) + h * HD + lane;
  float xk = (float)kqv[base];
  float xq = (float)kqv[base + EMB];
  float sk = xk, sq = xq;
#pragma unroll
  for (int m = 1; m < 64; m <<= 1) { sk += __shfl_xor(sk, m, 64); sq += __shfl_xor(sq, m, 64); }
  float dk = xk - sk * (1.f / 64.f);
  float dq = xq - sq * (1.f / 64.f);
  float vk = dk * dk, vq = dq * dq;
#pragma unroll
  for (int m = 1; m < 64; m <<= 1) { vk += __shfl_xor(vk, m, 64); vq += __shfl_xor(vq, m, 64); }
  float yk = (dk * rsqrtf(vk * (1.f / 64.f) + LNEPS) * kg[lane] + kb[lane]) * kscale;
  float yq = (dq * rsqrtf(vq * (1.f / 64.f) + LNEPS) * qg[lane] + qb[lane]) * qscale;
  int b = tok >> 11;
  int tt = tok & 2047;
  size_t o = ((size_t)(b * HEADS + h) * SEQ + tt) * HD + lane;
  kn[o] = (bf16)yk;
  qn[o] = (bf16)yq;
}

// ---------------- V transpose: [t][3072] (V at col 2048) -> [bh][64 d][2048 t] ----------------
__global__ void v_trans(const bf16* __restrict__ in, int ldin, bf16* __restrict__ out)
{
  __shared__ __align__(16) bf16 tile[64][72];
  int bh = blockIdx.y, jt = blockIdx.x;
  int b = bh >> 4, h = bh & 15;
  int t = threadIdx.x;
#pragma unroll
  for (int p = 0; p < 2; p++) {
    int rowj = p * 32 + (t >> 3);
    int cold = (t & 7) << 3;
    bf16x8 v = *reinterpret_cast<const bf16x8*>(
        &in[(size_t)(b * SEQ + jt * 64 + rowj) * ldin + h * HD + cold]);
    *reinterpret_cast<bf16x8*>(&tile[rowj][cold]) = v;
  }
  __syncthreads();
#pragma unroll
  for (int p = 0; p < 2; p++) {
    int rowd = p * 32 + (t >> 3);
    int colj = (t & 7) << 3;
    bf16x8 v;
#pragma unroll
    for (int jj = 0; jj < 8; jj++) v[jj] = tile[colj + jj][rowd];
    *reinterpret_cast<bf16x8*>(&out[((size_t)bh * HD + rowd) * SEQ + jt * 64 + colj]) = v;
  }
}

// ---------------- flash attention (causal), S^T formulation ----------------
// S^T = K * Q^T via 16x16x32 MFMA; its C-layout directly feeds P^T as the
// B-operand of 16x16x16 MFMA for O^T = V^T * P^T -> no LDS round-trip for P.
// Qn: [bh][t][64] (LN'd, *E^-.25). Kn: same *log2e. Vt: [bh][64][2048].
// 128 threads = 2 waves x 64 Q rows; j-tile 64, double-buffered staging.
__global__ __launch_bounds__(128, 3) void attn(
    const bf16* __restrict__ Qn, const bf16* __restrict__ Kn, const bf16* __restrict__ Vt,
    bf16* __restrict__ O)
{
  __shared__ __align__(16) bf16 Ks[2][64 * 64];
  __shared__ __align__(16) bf16 Vs[2][64 * 64];

  const int bh = blockIdx.y;
  const int i0 = ((int)gridDim.x - 1 - (int)blockIdx.x) * 128;   // LPT: biggest first
  const int t = threadIdx.x, wave = t >> 6, lane = t & 63;
  const int q = lane >> 4, ln = lane & 15;
  const int qbase = i0 + wave * 64;

  // Q fragments (B-operand of S^T mfma): qf[it][ks] = Q[i=qbase+it*16+ln][d=ks*32+q*8 ..+8]
  bf16x8 qf[4][2];
#pragma unroll
  for (int it = 0; it < 4; it++) {
    const bf16* qp = Qn + ((size_t)bh * SEQ + qbase + it * 16 + ln) * HD + q * 8;
    qf[it][0] = *reinterpret_cast<const bf16x8*>(qp);
    qf[it][1] = *reinterpret_cast<const bf16x8*>(qp + 32);
  }

  float lrow[4];
  f32x4 zero4 = {0.f, 0.f, 0.f, 0.f};
  f32x4 oacc[4][4];                       // [md][it] tiles of O^T[d][i]
#pragma unroll
  for (int it = 0; it < 4; it++) lrow[it] = 0.f;
#pragma unroll
  for (int md = 0; md < 4; md++)
#pragma unroll
    for (int it = 0; it < 4; it++) oacc[md][it] = zero4;

  // staging: 16B-chunk XOR swizzle; 128 threads x 4 chunks cover each 8KB tile
#define STAGE(J0, BUF) do {                                                              \
    _Pragma("unroll")                                                                    \
    for (int s = 0; s < 4; s++) {                                                        \
      int u = t * 8 + s * 1024;                                                          \
      int row = u >> 6;                                                                  \
      int csrc = ((u >> 3) & 7) ^ (row & 7);                                             \
      gld_lds16(Kn + ((size_t)bh * SEQ + (J0) + row) * HD + csrc * 8, &Ks[BUF][u]);      \
      gld_lds16(Vt + ((size_t)bh * HD + row) * SEQ + (J0) + csrc * 8, &Vs[BUF][u]);      \
    }                                                                                    \
  } while (0)

  const int nj = (i0 >> 6) + 2;
  STAGE(0, 0);

  for (int jt = 0; jt < nj; jt++) {
    const int j0 = jt * 64;
    const int cur = jt & 1;
    __syncthreads();                       // buf[cur] staged; old readers of buf[cur^1] done
    if (jt + 1 < nj) STAGE((jt + 1) * 64, cur ^ 1);

    if (j0 <= qbase + 63) {
      const bf16* KsC = Ks[cur];
      const bf16* VsC = Vs[cur];

#pragma unroll
      for (int jb = 0; jb < 4; jb++) {
        const int rowj = jb * 16 + ln;
        // K fragments (A-operand): K[j=j0+jb*16+ln][d=ks*32+q*8 ..+8]
        bf16x8 kf0 = *reinterpret_cast<const bf16x8*>(&KsC[rowj * 64 + ((q)     ^ (rowj & 7)) * 8]);
        bf16x8 kf1 = *reinterpret_cast<const bf16x8*>(&KsC[rowj * 64 + ((4 + q) ^ (rowj & 7)) * 8]);

        bf16x4 pkf[4];
        bool live[4];
#pragma unroll
        for (int it = 0; it < 4; it++) {
          live[it] = (j0 + jb * 16) <= (qbase + it * 16 + 15);  // tile has unmasked elems
          if (!live[it]) continue;
          f32x4 z = zero4;
          z = __builtin_amdgcn_mfma_f32_16x16x32_bf16(kf0, qf[it][0], z, 0, 0, 0);
          z = __builtin_amdgcn_mfma_f32_16x16x32_bf16(kf1, qf[it][1], z, 0, 0, 0);
          // z[r] = S^T[j = j0+jb*16+q*4+r][i = qbase+it*16+ln]
          if (j0 + jb * 16 + 15 > qbase + it * 16) {            // partial tile: mask
#pragma unroll
            for (int r = 0; r < 4; r++) {
              int jj = j0 + jb * 16 + q * 4 + r;
              int ii = qbase + it * 16 + ln;
              if (jj > ii) z[r] = -1.0e30f;
            }
          }
          // fixed-max softmax (|s*log2e| <= 2.9 after per-head LN): p = 2^s
          float p0 = exp2f(z[0]), p1 = exp2f(z[1]), p2 = exp2f(z[2]), p3 = exp2f(z[3]);
          lrow[it] += (p0 + p1) + (p2 + p3);
          bf16x4 pk = { (bf16)p0, (bf16)p1, (bf16)p2, (bf16)p3 };
          pkf[it] = pk;                    // == B-operand frag of 16x16x16 (k=j, n=i)
        }

        // O^T += V^T * P^T for this 16-j slab
#pragma unroll
        for (int md = 0; md < 4; md++) {
          const int rowd = md * 16 + ln;
          // V^T[d=md*16+ln][j = jb*16 + q*4 ..+4] (A-operand, 4 contiguous bf16)
          const bf16* vp = &VsC[rowd * 64 + (((jb * 2 + (q >> 1)) ^ (rowd & 7)) * 8) + (q & 1) * 4];
          bf16x4 vf = *reinterpret_cast<const bf16x4*>(vp);
#pragma unroll
          for (int it = 0; it < 4; it++)
            if (live[it]) oacc[md][it] = mfma_pv(vf, pkf[it], oacc[md][it]);
        }
      }
    }
  }
#undef STAGE

  // epilogue: reduce l over the 4 quads holding each column i, normalize, store
  float inv[4];
#pragma unroll
  for (int it = 0; it < 4; it++) {
    float s = lrow[it];
    s += __shfl_xor(s, 16, 64);
    s += __shfl_xor(s, 32, 64);
    inv[it] = 1.f / s;
  }
  const int b = bh >> 4, h = bh & 15;
#pragma unroll
  for (int md = 0; md < 4; md++)
#pragma unroll
    for (int it = 0; it < 4; it++) {
      bf16x4 o4 = { (bf16)(oacc[md][it][0] * inv[it]), (bf16)(oacc[md][it][1] * inv[it]),
                    (bf16)(oacc[md][it][2] * inv[it]), (bf16)(oacc[md][it][3] * inv[it]) };
      int row = qbase + it * 16 + ln;               // token
      int col = h * HD + md * 16 + q * 4;           // 4 consecutive d
      *reinterpret_cast<bf16x4*>(&O[(size_t)(b * SEQ + row) * EMB + col]) = o4;
    }
}

// ---------------- launch ----------------
extern "C" void kernel_launch(void* const* d_in, const int* in_sizes, int n_in,
                              void* d_out, int out_size, void* d_ws, size_t ws_size,
                              hipStream_t stream)
{
  const float* x   = (const float*)d_in[0];
  const float* Wk  = (const float*)d_in[1];
  const float* Wq  = (const float*)d_in[2];
  const float* Wv  = (const float*)d_in[3];
  const float* Wo  = (const float*)d_in[4];
  const float* bo  = (const float*)d_in[5];
  const float* klg = (const float*)d_in[6];
  const float* klb = (const float*)d_in[7];
  const float* qlg = (const float*)d_in[8];
  const float* qlb = (const float*)d_in[9];
  float* out = (float*)d_out;

  char* ws = (char*)d_ws;
  const size_t OFF_XB  = 0;
  const size_t OFF_WB  = OFF_XB  + (size_t)BT * EMB * 2;
  const size_t OFF_KQV = OFF_WB  + (size_t)4 * EMB * EMB * 2;
  const size_t OFF_KN  = OFF_KQV + (size_t)BT * 3 * EMB * 2;
  const size_t OFF_QN  = OFF_KN  + (size_t)BT * EMB * 2;
  const size_t OFF_VT  = OFF_QN  + (size_t)BT * EMB * 2;
  const size_t OFF_END = OFF_VT  + (size_t)BT * EMB * 2;
  if (ws_size < OFF_END) return;

  bf16* xb   = (bf16*)(ws + OFF_XB);
  bf16* wb   = (bf16*)(ws + OFF_WB);
  bf16* kqv  = (bf16*)(ws + OFF_KQV);
  bf16* kn   = (bf16*)(ws + OFF_KN);
  bf16* qn   = (bf16*)(ws + OFF_QN);
  bf16* vt   = (bf16*)(ws + OFF_VT);
  bf16* ob   = (bf16*)(ws + OFF_KQV);    // alias: KQV dead after ln/v_trans

  cvt_f32_bf16<<<(BT * EMB / 4) / 256, 256, 0, stream>>>(x, xb, BT * EMB / 4);
  cvt_w4<<<(4 * EMB * EMB / 4) / 256, 256, 0, stream>>>(Wk, Wq, Wv, Wo, wb);

  gemm_bt<0><<<dim3(3 * EMB / 128, BT / 128), 256, 0, stream>>>(
      xb, wb, kqv, (float*)nullptr, (const float*)nullptr, BT, 3 * EMB, EMB);

  ln_kq<<<BT * HEADS / 4, 256, 0, stream>>>(kqv, kn, qn, klg, klb, qlg, qlb,
                                            QK_SCALE * LOG2E, QK_SCALE);
  v_trans<<<dim3(SEQ / 64, BATCH * HEADS), 256, 0, stream>>>(kqv + 2 * EMB, 3 * EMB, vt);

  attn<<<dim3(SEQ / 128, BATCH * HEADS), 128, 0, stream>>>(qn, kn, vt, ob);

  gemm_bt<1><<<dim3(EMB / 128, BT / 128), 256, 0, stream>>>(
      ob, wb + (size_t)3 * EMB * EMB, (bf16*)nullptr, out, bo, BT, EMB, EMB);
}

// Round 7
// 358.157 us; speedup vs baseline: 1.1097x; 1.1097x over previous
//
#include <hip/hip_runtime.h>
#include <hip/hip_bf16.h>
#include <cstdint>

#define EMB 1024
#define HEADS 16
#define HD 64
#define BATCH 4
#define SEQ 2048
#define BT (BATCH*SEQ)                 // 8192 tokens
#define LNEPS 1e-5f
#define QK_SCALE 0.17677669529663687f  // 1024^-0.25
#define LOG2E 1.4426950408889634f

typedef __bf16 bf16;
typedef __bf16 bf16x8 __attribute__((ext_vector_type(8)));
typedef __bf16 bf16x4 __attribute__((ext_vector_type(4)));
typedef float  f32x4  __attribute__((ext_vector_type(4)));
typedef short  s16x4  __attribute__((ext_vector_type(4)));

typedef const __attribute__((address_space(1))) void* gas_ptr;
typedef __attribute__((address_space(3))) void*       las_ptr;

__device__ __forceinline__ void gld_lds16(const void* g, void* l) {
  __builtin_amdgcn_global_load_lds((gas_ptr)g, (las_ptr)l, 16, 0, 0);
}

// PV matmul: 16x16x16 bf16 MFMA (C-layout of S^T == B-layout of this shape).
__device__ __forceinline__ f32x4 mfma_pv(bf16x4 a, bf16x4 b, f32x4 c) {
  return __builtin_amdgcn_mfma_f32_16x16x16bf16_1k(
      __builtin_bit_cast(s16x4, a), __builtin_bit_cast(s16x4, b), c, 0, 0, 0);
}

// ---------------- fp32 -> bf16 conversion ----------------
__global__ void cvt_f32_bf16(const float* __restrict__ src, bf16* __restrict__ dst, int n4) {
  int i = blockIdx.x * blockDim.x + threadIdx.x;
  if (i >= n4) return;
  float4 f = reinterpret_cast<const float4*>(src)[i];
  bf16x4 o = { (bf16)f.x, (bf16)f.y, (bf16)f.z, (bf16)f.w };
  reinterpret_cast<bf16x4*>(dst)[i] = o;
}

// 4 weight matrices (1024x1024 each) -> contiguous bf16 [4*1024][1024]
__global__ void cvt_w4(const float* __restrict__ w0, const float* __restrict__ w1,
                       const float* __restrict__ w2, const float* __restrict__ w3,
                       bf16* __restrict__ dst) {
  int i = blockIdx.x * blockDim.x + threadIdx.x;   // over 4*262144 float4s
  int sel = i >> 18;
  int j = i & 262143;
  const float* s = (sel == 0) ? w0 : (sel == 1) ? w1 : (sel == 2) ? w2 : w3;
  float4 f = reinterpret_cast<const float4*>(s)[j];
  bf16x4 o = { (bf16)f.x, (bf16)f.y, (bf16)f.z, (bf16)f.w };
  reinterpret_cast<bf16x4*>(dst)[i] = o;
}

// ---------------- m97-style GEMM: C[M][N] = A[M][K] * B[N][K]^T ----------------
template<int OUTF32>
__global__ __launch_bounds__(256, 2) void gemm_bt(
    const bf16* __restrict__ A, const bf16* __restrict__ Bm,
    bf16* __restrict__ Cb, float* __restrict__ Cf, const float* __restrict__ bias,
    int M, int N, int K)
{
  __shared__ __align__(16) bf16 As[128 * 32];
  __shared__ __align__(16) bf16 Bs[128 * 32];

  const int t    = threadIdx.x;
  const int lane = t & 63;
  const int wave = t >> 6;
  const int q    = lane >> 4;
  const int ln   = lane & 15;
  const int m0   = blockIdx.y * 128;
  const int n0   = blockIdx.x * 128;
  const int wm   = (wave >> 1) * 64;
  const int wn   = (wave & 1) * 64;

  const int r0 = t >> 2;
  const int c0 = (t & 3) << 3;

  f32x4 zero4 = {0.f, 0.f, 0.f, 0.f};
  f32x4 acc[4][4];
#pragma unroll
  for (int i = 0; i < 4; i++)
#pragma unroll
    for (int j = 0; j < 4; j++) acc[i][j] = zero4;

  for (int k0 = 0; k0 < K; k0 += 32) {
    __syncthreads();
    const bf16* ga = A  + (size_t)(m0 + r0) * K + k0 + c0;
    const bf16* gb = Bm + (size_t)(n0 + r0) * K + k0 + c0;
    gld_lds16(ga,                  &As[t * 8]);
    gld_lds16(ga + (size_t)64 * K, &As[t * 8 + 2048]);
    gld_lds16(gb,                  &Bs[t * 8]);
    gld_lds16(gb + (size_t)64 * K, &Bs[t * 8 + 2048]);
    __syncthreads();

    bf16x8 af[4], bfr[4];
#pragma unroll
    for (int mi = 0; mi < 4; mi++)
      af[mi] = *reinterpret_cast<const bf16x8*>(&As[(wm + mi * 16 + ln) * 32 + q * 8]);
#pragma unroll
    for (int ni = 0; ni < 4; ni++)
      bfr[ni] = *reinterpret_cast<const bf16x8*>(&Bs[(wn + ni * 16 + ln) * 32 + q * 8]);
#pragma unroll
    for (int mi = 0; mi < 4; mi++)
#pragma unroll
      for (int ni = 0; ni < 4; ni++)
        acc[mi][ni] = __builtin_amdgcn_mfma_f32_16x16x32_bf16(af[mi], bfr[ni], acc[mi][ni], 0, 0, 0);
  }

#pragma unroll
  for (int mi = 0; mi < 4; mi++) {
#pragma unroll
    for (int ni = 0; ni < 4; ni++) {
#pragma unroll
      for (int r = 0; r < 4; r++) {
        int row = m0 + wm + mi * 16 + q * 4 + r;
        int col = n0 + wn + ni * 16 + ln;
        float v = acc[mi][ni][r];
        if (OUTF32) Cf[(size_t)row * N + col] = v + bias[col];
        else        Cb[(size_t)row * N + col] = (bf16)v;
      }
    }
  }
}

// ---------------- per-head LayerNorm for K and Q in one pass ----------------
// kqv: [8192][3072]; K at col 0, Q at col 1024. Outputs [bh][t][64].
// kscale includes log2(e) so attention can use exp2 directly.
__global__ void ln_kq(const bf16* __restrict__ kqv,
                      bf16* __restrict__ kn, bf16* __restrict__ qn,
                      const float* __restrict__ kg, const float* __restrict__ kb,
                      const float* __restrict__ qg, const float* __restrict__ qb,
                      float kscale, float qscale)
{
  int wave = threadIdx.x >> 6, lane = threadIdx.x & 63;
  int row = blockIdx.x * 4 + wave;        // row = t*16 + h
  int tok = row >> 4, h = row & 15;
  size_t base = (size_t)tok * (3 * EMB) + h * HD + lane;
  float xk = (float)kqv[base];
  float xq = (float)kqv[base + EMB];
  float sk = xk, sq = xq;
#pragma unroll
  for (int m = 1; m < 64; m <<= 1) { sk += __shfl_xor(sk, m, 64); sq += __shfl_xor(sq, m, 64); }
  float dk = xk - sk * (1.f / 64.f);
  float dq = xq - sq * (1.f / 64.f);
  float vk = dk * dk, vq = dq * dq;
#pragma unroll
  for (int m = 1; m < 64; m <<= 1) { vk += __shfl_xor(vk, m, 64); vq += __shfl_xor(vq, m, 64); }
  float yk = (dk * rsqrtf(vk * (1.f / 64.f) + LNEPS) * kg[lane] + kb[lane]) * kscale;
  float yq = (dq * rsqrtf(vq * (1.f / 64.f) + LNEPS) * qg[lane] + qb[lane]) * qscale;
  int b = tok >> 11;
  int tt = tok & 2047;
  size_t o = ((size_t)(b * HEADS + h) * SEQ + tt) * HD + lane;
  kn[o] = (bf16)yk;
  qn[o] = (bf16)yq;
}

// ---------------- V transpose: [t][3072] (V at col 2048) -> [bh][64 d][2048 t] ----------------
__global__ void v_trans(const bf16* __restrict__ in, int ldin, bf16* __restrict__ out)
{
  __shared__ __align__(16) bf16 tile[64][72];
  int bh = blockIdx.y, jt = blockIdx.x;
  int b = bh >> 4, h = bh & 15;
  int t = threadIdx.x;
#pragma unroll
  for (int p = 0; p < 2; p++) {
    int rowj = p * 32 + (t >> 3);
    int cold = (t & 7) << 3;
    bf16x8 v = *reinterpret_cast<const bf16x8*>(
        &in[(size_t)(b * SEQ + jt * 64 + rowj) * ldin + h * HD + cold]);
    *reinterpret_cast<bf16x8*>(&tile[rowj][cold]) = v;
  }
  __syncthreads();
#pragma unroll
  for (int p = 0; p < 2; p++) {
    int rowd = p * 32 + (t >> 3);
    int colj = (t & 7) << 3;
    bf16x8 v;
#pragma unroll
    for (int jj = 0; jj < 8; jj++) v[jj] = tile[colj + jj][rowd];
    *reinterpret_cast<bf16x8*>(&out[((size_t)bh * HD + rowd) * SEQ + jt * 64 + colj]) = v;
  }
}

// ---------------- flash attention (causal), S^T formulation, occupancy-first ----------------
// S^T = K*Q^T (16x16x32); C-layout == B-operand of 16x16x16 -> PV from registers.
// Grid: 32 i-tiles (64 rows) x 64 bh; 128 threads = 2 waves x 32 Q rows.
// Single 16KB K/V LDS buffer (10 blocks/CU LDS cap); 8 blocks/CU from grid.
__global__ __launch_bounds__(128, 4) void attn(
    const bf16* __restrict__ Qn, const bf16* __restrict__ Kn, const bf16* __restrict__ Vt,
    bf16* __restrict__ O)
{
  __shared__ __align__(16) bf16 Ks[64 * 64];
  __shared__ __align__(16) bf16 Vs[64 * 64];

  const int bh = blockIdx.y;
  const int i0 = ((int)gridDim.x - 1 - (int)blockIdx.x) * 64;   // LPT: biggest first
  const int t = threadIdx.x, wave = t >> 6, lane = t & 63;
  const int q = lane >> 4, ln = lane & 15;
  const int qbase = i0 + wave * 32;

  // Q fragments (B-operand of S^T mfma): qf[it][ks] = Q[i=qbase+it*16+ln][d=ks*32+q*8 ..+8]
  bf16x8 qf[2][2];
#pragma unroll
  for (int it = 0; it < 2; it++) {
    const bf16* qp = Qn + ((size_t)bh * SEQ + qbase + it * 16 + ln) * HD + q * 8;
    qf[it][0] = *reinterpret_cast<const bf16x8*>(qp);
    qf[it][1] = *reinterpret_cast<const bf16x8*>(qp + 32);
  }

  float lrow[2] = {0.f, 0.f};
  f32x4 zero4 = {0.f, 0.f, 0.f, 0.f};
  f32x4 oacc[4][2];                       // [md][it] tiles of O^T[d][i]
#pragma unroll
  for (int md = 0; md < 4; md++)
#pragma unroll
    for (int it = 0; it < 2; it++) oacc[md][it] = zero4;

  const int nj = (i0 >> 6) + 1;
  for (int jt = 0; jt < nj; jt++) {
    const int j0 = jt * 64;
    // stage K tile [64 j][64 d] and V^T tile [64 d][64 j], 16B-chunk XOR swizzle
#pragma unroll
    for (int s = 0; s < 4; s++) {
      int u = t * 8 + s * 1024;
      int row = u >> 6;
      int csrc = ((u >> 3) & 7) ^ (row & 7);
      gld_lds16(Kn + ((size_t)bh * SEQ + j0 + row) * HD + csrc * 8, &Ks[u]);
      gld_lds16(Vt + ((size_t)bh * HD + row) * SEQ + j0 + csrc * 8, &Vs[u]);
    }
    __syncthreads();                       // drains vmcnt(0): tile visible

#pragma unroll
    for (int jb = 0; jb < 4; jb++) {
      const int rowj = jb * 16 + ln;
      // K fragments (A-operand): K[j=j0+jb*16+ln][d=ks*32+q*8 ..+8]
      bf16x8 kf0 = *reinterpret_cast<const bf16x8*>(&Ks[rowj * 64 + ((q)     ^ (rowj & 7)) * 8]);
      bf16x8 kf1 = *reinterpret_cast<const bf16x8*>(&Ks[rowj * 64 + ((4 + q) ^ (rowj & 7)) * 8]);

      bf16x4 pkf[2];
      bool live[2];
#pragma unroll
      for (int it = 0; it < 2; it++) {
        live[it] = (j0 + jb * 16) <= (qbase + it * 16 + 15);  // slab has unmasked elems
        if (!live[it]) continue;
        f32x4 z = zero4;
        z = __builtin_amdgcn_mfma_f32_16x16x32_bf16(kf0, qf[it][0], z, 0, 0, 0);
        z = __builtin_amdgcn_mfma_f32_16x16x32_bf16(kf1, qf[it][1], z, 0, 0, 0);
        // z[r] = S^T[j = j0+jb*16+q*4+r][i = qbase+it*16+ln]
        if (j0 + jb * 16 + 15 > qbase + it * 16) {            // partial slab: mask
#pragma unroll
          for (int r = 0; r < 4; r++) {
            int jj = j0 + jb * 16 + q * 4 + r;
            int ii = qbase + it * 16 + ln;
            if (jj > ii) z[r] = -1.0e30f;
          }
        }
        // fixed-max softmax (|s*log2e| <= 2.9 after per-head LN): p = 2^s
        float p0 = exp2f(z[0]), p1 = exp2f(z[1]), p2 = exp2f(z[2]), p3 = exp2f(z[3]);
        lrow[it] += (p0 + p1) + (p2 + p3);
        bf16x4 pk = { (bf16)p0, (bf16)p1, (bf16)p2, (bf16)p3 };
        pkf[it] = pk;                      // == B-operand frag of 16x16x16 (k=j, n=i)
      }

      // O^T += V^T * P^T for this 16-j slab
#pragma unroll
      for (int md = 0; md < 4; md++) {
        const int rowd = md * 16 + ln;
        // V^T[d=md*16+ln][j = jb*16 + q*4 ..+4] (A-operand, 4 contiguous bf16)
        const bf16* vp = &Vs[rowd * 64 + (((jb * 2 + (q >> 1)) ^ (rowd & 7)) * 8) + (q & 1) * 4];
        bf16x4 vf = *reinterpret_cast<const bf16x4*>(vp);
#pragma unroll
        for (int it = 0; it < 2; it++)
          if (live[it]) oacc[md][it] = mfma_pv(vf, pkf[it], oacc[md][it]);
      }
    }
    __syncthreads();                       // all reads done before next stage overwrites
  }

  // epilogue: reduce l over the 4 quads holding each column i, normalize, store
  float inv[2];
#pragma unroll
  for (int it = 0; it < 2; it++) {
    float s = lrow[it];
    s += __shfl_xor(s, 16, 64);
    s += __shfl_xor(s, 32, 64);
    inv[it] = 1.f / s;
  }
  const int b = bh >> 4, h = bh & 15;
#pragma unroll
  for (int md = 0; md < 4; md++)
#pragma unroll
    for (int it = 0; it < 2; it++) {
      bf16x4 o4 = { (bf16)(oacc[md][it][0] * inv[it]), (bf16)(oacc[md][it][1] * inv[it]),
                    (bf16)(oacc[md][it][2] * inv[it]), (bf16)(oacc[md][it][3] * inv[it]) };
      int row = qbase + it * 16 + ln;               // token
      int col = h * HD + md * 16 + q * 4;           // 4 consecutive d
      *reinterpret_cast<bf16x4*>(&O[(size_t)(b * SEQ + row) * EMB + col]) = o4;
    }
}

// ---------------- launch ----------------
extern "C" void kernel_launch(void* const* d_in, const int* in_sizes, int n_in,
                              void* d_out, int out_size, void* d_ws, size_t ws_size,
                              hipStream_t stream)
{
  const float* x   = (const float*)d_in[0];
  const float* Wk  = (const float*)d_in[1];
  const float* Wq  = (const float*)d_in[2];
  const float* Wv  = (const float*)d_in[3];
  const float* Wo  = (const float*)d_in[4];
  const float* bo  = (const float*)d_in[5];
  const float* klg = (const float*)d_in[6];
  const float* klb = (const float*)d_in[7];
  const float* qlg = (const float*)d_in[8];
  const float* qlb = (const float*)d_in[9];
  float* out = (float*)d_out;

  char* ws = (char*)d_ws;
  const size_t OFF_XB  = 0;
  const size_t OFF_WB  = OFF_XB  + (size_t)BT * EMB * 2;
  const size_t OFF_KQV = OFF_WB  + (size_t)4 * EMB * EMB * 2;
  const size_t OFF_KN  = OFF_KQV + (size_t)BT * 3 * EMB * 2;
  const size_t OFF_QN  = OFF_KN  + (size_t)BT * EMB * 2;
  const size_t OFF_VT  = OFF_QN  + (size_t)BT * EMB * 2;
  const size_t OFF_END = OFF_VT  + (size_t)BT * EMB * 2;
  if (ws_size < OFF_END) return;

  bf16* xb   = (bf16*)(ws + OFF_XB);
  bf16* wb   = (bf16*)(ws + OFF_WB);
  bf16* kqv  = (bf16*)(ws + OFF_KQV);
  bf16* kn   = (bf16*)(ws + OFF_KN);
  bf16* qn   = (bf16*)(ws + OFF_QN);
  bf16* vt   = (bf16*)(ws + OFF_VT);
  bf16* ob   = (bf16*)(ws + OFF_KQV);    // alias: KQV dead after ln/v_trans

  cvt_f32_bf16<<<(BT * EMB / 4) / 256, 256, 0, stream>>>(x, xb, BT * EMB / 4);
  cvt_w4<<<(4 * EMB * EMB / 4) / 256, 256, 0, stream>>>(Wk, Wq, Wv, Wo, wb);

  gemm_bt<0><<<dim3(3 * EMB / 128, BT / 128), 256, 0, stream>>>(
      xb, wb, kqv, (float*)nullptr, (const float*)nullptr, BT, 3 * EMB, EMB);

  ln_kq<<<BT * HEADS / 4, 256, 0, stream>>>(kqv, kn, qn, klg, klb, qlg, qlb,
                                            QK_SCALE * LOG2E, QK_SCALE);
  v_trans<<<dim3(SEQ / 64, BATCH * HEADS), 256, 0, stream>>>(kqv + 2 * EMB, 3 * EMB, vt);

  attn<<<dim3(SEQ / 64, BATCH * HEADS), 128, 0, stream>>>(qn, kn, vt, ob);

  gemm_bt<1><<<dim3(EMB / 128, BT / 128), 256, 0, stream>>>(
      ob, wb + (size_t)3 * EMB * EMB, (bf16*)nullptr, out, bo, BT, EMB, EMB);
}

// Round 8
// 348.791 us; speedup vs baseline: 1.1395x; 1.0269x over previous
//
#include <hip/hip_runtime.h>
#include <hip/hip_bf16.h>
#include <cstdint>

#define EMB 1024
#define HEADS 16
#define HD 64
#define BATCH 4
#define SEQ 2048
#define BT (BATCH*SEQ)                 // 8192 tokens
#define LNEPS 1e-5f
#define QK_SCALE 0.17677669529663687f  // 1024^-0.25
#define LOG2E 1.4426950408889634f

typedef __bf16 bf16;
typedef __bf16 bf16x8 __attribute__((ext_vector_type(8)));
typedef __bf16 bf16x4 __attribute__((ext_vector_type(4)));
typedef float  f32x4  __attribute__((ext_vector_type(4)));
typedef short  s16x4  __attribute__((ext_vector_type(4)));

typedef const __attribute__((address_space(1))) void* gas_ptr;
typedef __attribute__((address_space(3))) void*       las_ptr;

__device__ __forceinline__ void gld_lds16(const void* g, void* l) {
  __builtin_amdgcn_global_load_lds((gas_ptr)g, (las_ptr)l, 16, 0, 0);
}

// PV matmul: 16x16x16 bf16 MFMA (C-layout of S^T == B-layout of this shape).
__device__ __forceinline__ f32x4 mfma_pv(bf16x4 a, bf16x4 b, f32x4 c) {
  return __builtin_amdgcn_mfma_f32_16x16x16bf16_1k(
      __builtin_bit_cast(s16x4, a), __builtin_bit_cast(s16x4, b), c, 0, 0, 0);
}

// ---------------- fp32 -> bf16 conversion ----------------
__global__ void cvt_f32_bf16(const float* __restrict__ src, bf16* __restrict__ dst, int n4) {
  int i = blockIdx.x * blockDim.x + threadIdx.x;
  if (i >= n4) return;
  float4 f = reinterpret_cast<const float4*>(src)[i];
  bf16x4 o = { (bf16)f.x, (bf16)f.y, (bf16)f.z, (bf16)f.w };
  reinterpret_cast<bf16x4*>(dst)[i] = o;
}

// 4 weight matrices (1024x1024 each) -> contiguous bf16 [4*1024][1024]
__global__ void cvt_w4(const float* __restrict__ w0, const float* __restrict__ w1,
                       const float* __restrict__ w2, const float* __restrict__ w3,
                       bf16* __restrict__ dst) {
  int i = blockIdx.x * blockDim.x + threadIdx.x;   // over 4*262144 float4s
  int sel = i >> 18;
  int j = i & 262143;
  const float* s = (sel == 0) ? w0 : (sel == 1) ? w1 : (sel == 2) ? w2 : w3;
  float4 f = reinterpret_cast<const float4*>(s)[j];
  bf16x4 o = { (bf16)f.x, (bf16)f.y, (bf16)f.z, (bf16)f.w };
  reinterpret_cast<bf16x4*>(dst)[i] = o;
}

// ---------------- m97-style GEMM: C[M][N] = A[M][K] * B[N][K]^T ----------------
template<int OUTF32>
__global__ __launch_bounds__(256, 2) void gemm_bt(
    const bf16* __restrict__ A, const bf16* __restrict__ Bm,
    bf16* __restrict__ Cb, float* __restrict__ Cf, const float* __restrict__ bias,
    int M, int N, int K)
{
  __shared__ __align__(16) bf16 As[128 * 32];
  __shared__ __align__(16) bf16 Bs[128 * 32];

  const int t    = threadIdx.x;
  const int lane = t & 63;
  const int wave = t >> 6;
  const int q    = lane >> 4;
  const int ln   = lane & 15;
  const int m0   = blockIdx.y * 128;
  const int n0   = blockIdx.x * 128;
  const int wm   = (wave >> 1) * 64;
  const int wn   = (wave & 1) * 64;

  const int r0 = t >> 2;
  const int c0 = (t & 3) << 3;

  f32x4 zero4 = {0.f, 0.f, 0.f, 0.f};
  f32x4 acc[4][4];
#pragma unroll
  for (int i = 0; i < 4; i++)
#pragma unroll
    for (int j = 0; j < 4; j++) acc[i][j] = zero4;

  for (int k0 = 0; k0 < K; k0 += 32) {
    __syncthreads();
    const bf16* ga = A  + (size_t)(m0 + r0) * K + k0 + c0;
    const bf16* gb = Bm + (size_t)(n0 + r0) * K + k0 + c0;
    gld_lds16(ga,                  &As[t * 8]);
    gld_lds16(ga + (size_t)64 * K, &As[t * 8 + 2048]);
    gld_lds16(gb,                  &Bs[t * 8]);
    gld_lds16(gb + (size_t)64 * K, &Bs[t * 8 + 2048]);
    __syncthreads();

    bf16x8 af[4], bfr[4];
#pragma unroll
    for (int mi = 0; mi < 4; mi++)
      af[mi] = *reinterpret_cast<const bf16x8*>(&As[(wm + mi * 16 + ln) * 32 + q * 8]);
#pragma unroll
    for (int ni = 0; ni < 4; ni++)
      bfr[ni] = *reinterpret_cast<const bf16x8*>(&Bs[(wn + ni * 16 + ln) * 32 + q * 8]);
#pragma unroll
    for (int mi = 0; mi < 4; mi++)
#pragma unroll
      for (int ni = 0; ni < 4; ni++)
        acc[mi][ni] = __builtin_amdgcn_mfma_f32_16x16x32_bf16(af[mi], bfr[ni], acc[mi][ni], 0, 0, 0);
  }

#pragma unroll
  for (int mi = 0; mi < 4; mi++) {
#pragma unroll
    for (int ni = 0; ni < 4; ni++) {
#pragma unroll
      for (int r = 0; r < 4; r++) {
        int row = m0 + wm + mi * 16 + q * 4 + r;
        int col = n0 + wn + ni * 16 + ln;
        float v = acc[mi][ni][r];
        if (OUTF32) Cf[(size_t)row * N + col] = v + bias[col];
        else        Cb[(size_t)row * N + col] = (bf16)v;
      }
    }
  }
}

// ---------------- per-head LayerNorm for K and Q in one pass ----------------
// kqv: [8192][3072]; K at col 0, Q at col 1024. Outputs [bh][t][64].
// kscale includes log2(e) so attention can use exp2 directly.
__global__ void ln_kq(const bf16* __restrict__ kqv,
                      bf16* __restrict__ kn, bf16* __restrict__ qn,
                      const float* __restrict__ kg, const float* __restrict__ kb,
                      const float* __restrict__ qg, const float* __restrict__ qb,
                      float kscale, float qscale)
{
  int wave = threadIdx.x >> 6, lane = threadIdx.x & 63;
  int row = blockIdx.x * 4 + wave;        // row = t*16 + h
  int tok = row >> 4, h = row & 15;
  size_t base = (size_t)tok * (3 * EMB) + h * HD + lane;
  float xk = (float)kqv[base];
  float xq = (float)kqv[base + EMB];
  float sk = xk, sq = xq;
#pragma unroll
  for (int m = 1; m < 64; m <<= 1) { sk += __shfl_xor(sk, m, 64); sq += __shfl_xor(sq, m, 64); }
  float dk = xk - sk * (1.f / 64.f);
  float dq = xq - sq * (1.f / 64.f);
  float vk = dk * dk, vq = dq * dq;
#pragma unroll
  for (int m = 1; m < 64; m <<= 1) { vk += __shfl_xor(vk, m, 64); vq += __shfl_xor(vq, m, 64); }
  float yk = (dk * rsqrtf(vk * (1.f / 64.f) + LNEPS) * kg[lane] + kb[lane]) * kscale;
  float yq = (dq * rsqrtf(vq * (1.f / 64.f) + LNEPS) * qg[lane] + qb[lane]) * qscale;
  int b = tok >> 11;
  int tt = tok & 2047;
  size_t o = ((size_t)(b * HEADS + h) * SEQ + tt) * HD + lane;
  kn[o] = (bf16)yk;
  qn[o] = (bf16)yq;
}

// ---------------- V transpose: [t][3072] (V at col 2048) -> [bh][64 d][2048 t] ----------------
__global__ void v_trans(const bf16* __restrict__ in, int ldin, bf16* __restrict__ out)
{
  __shared__ __align__(16) bf16 tile[64][72];
  int bh = blockIdx.y, jt = blockIdx.x;
  int b = bh >> 4, h = bh & 15;
  int t = threadIdx.x;
#pragma unroll
  for (int p = 0; p < 2; p++) {
    int rowj = p * 32 + (t >> 3);
    int cold = (t & 7) << 3;
    bf16x8 v = *reinterpret_cast<const bf16x8*>(
        &in[(size_t)(b * SEQ + jt * 64 + rowj) * ldin + h * HD + cold]);
    *reinterpret_cast<bf16x8*>(&tile[rowj][cold]) = v;
  }
  __syncthreads();
#pragma unroll
  for (int p = 0; p < 2; p++) {
    int rowd = p * 32 + (t >> 3);
    int colj = (t & 7) << 3;
    bf16x8 v;
#pragma unroll
    for (int jj = 0; jj < 8; jj++) v[jj] = tile[colj + jj][rowd];
    *reinterpret_cast<bf16x8*>(&out[((size_t)bh * HD + rowd) * SEQ + jt * 64 + colj]) = v;
  }
}

// ---------------- flash attention (causal), S^T formulation, CU-balanced ----------------
// S^T = K*Q^T (16x16x32); C-layout == B-operand of 16x16x16 -> PV from registers.
// Grid: 32 x 64 bh; i-tile = (bx+by)&31 shears the work assignment so each CU's
// 8 co-resident blocks span different i-tile sizes (uniform ~132 tile-steps/CU).
// 128 threads = 2 waves x 32 Q rows; single 16KB K/V LDS buffer.
__global__ __launch_bounds__(128, 4) void attn(
    const bf16* __restrict__ Qn, const bf16* __restrict__ Kn, const bf16* __restrict__ Vt,
    bf16* __restrict__ O)
{
  __shared__ __align__(16) bf16 Ks[64 * 64];
  __shared__ __align__(16) bf16 Vs[64 * 64];

  const int bh = blockIdx.y;
  const int itile = ((int)blockIdx.x + (int)blockIdx.y) & 31;   // decorrelate from CU
  const int i0 = itile * 64;
  const int t = threadIdx.x, wave = t >> 6, lane = t & 63;
  const int q = lane >> 4, ln = lane & 15;
  const int qbase = i0 + wave * 32;

  // Q fragments (B-operand of S^T mfma): qf[it][ks] = Q[i=qbase+it*16+ln][d=ks*32+q*8 ..+8]
  bf16x8 qf[2][2];
#pragma unroll
  for (int it = 0; it < 2; it++) {
    const bf16* qp = Qn + ((size_t)bh * SEQ + qbase + it * 16 + ln) * HD + q * 8;
    qf[it][0] = *reinterpret_cast<const bf16x8*>(qp);
    qf[it][1] = *reinterpret_cast<const bf16x8*>(qp + 32);
  }

  float lrow[2] = {0.f, 0.f};
  f32x4 zero4 = {0.f, 0.f, 0.f, 0.f};
  f32x4 oacc[4][2];                       // [md][it] tiles of O^T[d][i]
#pragma unroll
  for (int md = 0; md < 4; md++)
#pragma unroll
    for (int it = 0; it < 2; it++) oacc[md][it] = zero4;

  const int nj = (i0 >> 6) + 1;
  for (int jt = 0; jt < nj; jt++) {
    const int j0 = jt * 64;
    // stage K tile [64 j][64 d] and V^T tile [64 d][64 j], 16B-chunk XOR swizzle
#pragma unroll
    for (int s = 0; s < 4; s++) {
      int u = t * 8 + s * 1024;
      int row = u >> 6;
      int csrc = ((u >> 3) & 7) ^ (row & 7);
      gld_lds16(Kn + ((size_t)bh * SEQ + j0 + row) * HD + csrc * 8, &Ks[u]);
      gld_lds16(Vt + ((size_t)bh * HD + row) * SEQ + j0 + csrc * 8, &Vs[u]);
    }
    __syncthreads();                       // drains vmcnt(0): tile visible

#pragma unroll
    for (int jb = 0; jb < 4; jb++) {
      const int rowj = jb * 16 + ln;
      // K fragments (A-operand): K[j=j0+jb*16+ln][d=ks*32+q*8 ..+8]
      bf16x8 kf0 = *reinterpret_cast<const bf16x8*>(&Ks[rowj * 64 + ((q)     ^ (rowj & 7)) * 8]);
      bf16x8 kf1 = *reinterpret_cast<const bf16x8*>(&Ks[rowj * 64 + ((4 + q) ^ (rowj & 7)) * 8]);

      bf16x4 pkf[2];
      bool live[2];
#pragma unroll
      for (int it = 0; it < 2; it++) {
        live[it] = (j0 + jb * 16) <= (qbase + it * 16 + 15);  // slab has unmasked elems
        if (!live[it]) continue;
        f32x4 z = zero4;
        z = __builtin_amdgcn_mfma_f32_16x16x32_bf16(kf0, qf[it][0], z, 0, 0, 0);
        z = __builtin_amdgcn_mfma_f32_16x16x32_bf16(kf1, qf[it][1], z, 0, 0, 0);
        // z[r] = S^T[j = j0+jb*16+q*4+r][i = qbase+it*16+ln]
        if (j0 + jb * 16 + 15 > qbase + it * 16) {            // partial slab: mask
#pragma unroll
          for (int r = 0; r < 4; r++) {
            int jj = j0 + jb * 16 + q * 4 + r;
            int ii = qbase + it * 16 + ln;
            if (jj > ii) z[r] = -1.0e30f;
          }
        }
        // fixed-max softmax (|s*log2e| <= 2.9 after per-head LN): p = 2^s
        float p0 = exp2f(z[0]), p1 = exp2f(z[1]), p2 = exp2f(z[2]), p3 = exp2f(z[3]);
        lrow[it] += (p0 + p1) + (p2 + p3);
        bf16x4 pk = { (bf16)p0, (bf16)p1, (bf16)p2, (bf16)p3 };
        pkf[it] = pk;                      // == B-operand frag of 16x16x16 (k=j, n=i)
      }

      // O^T += V^T * P^T for this 16-j slab
#pragma unroll
      for (int md = 0; md < 4; md++) {
        const int rowd = md * 16 + ln;
        // V^T[d=md*16+ln][j = jb*16 + q*4 ..+4] (A-operand, 4 contiguous bf16)
        const bf16* vp = &Vs[rowd * 64 + (((jb * 2 + (q >> 1)) ^ (rowd & 7)) * 8) + (q & 1) * 4];
        bf16x4 vf = *reinterpret_cast<const bf16x4*>(vp);
#pragma unroll
        for (int it = 0; it < 2; it++)
          if (live[it]) oacc[md][it] = mfma_pv(vf, pkf[it], oacc[md][it]);
      }
    }
    __syncthreads();                       // all reads done before next stage overwrites
  }

  // epilogue: reduce l over the 4 quads holding each column i, normalize, store
  float inv[2];
#pragma unroll
  for (int it = 0; it < 2; it++) {
    float s = lrow[it];
    s += __shfl_xor(s, 16, 64);
    s += __shfl_xor(s, 32, 64);
    inv[it] = 1.f / s;
  }
  const int b = bh >> 4, h = bh & 15;
#pragma unroll
  for (int md = 0; md < 4; md++)
#pragma unroll
    for (int it = 0; it < 2; it++) {
      bf16x4 o4 = { (bf16)(oacc[md][it][0] * inv[it]), (bf16)(oacc[md][it][1] * inv[it]),
                    (bf16)(oacc[md][it][2] * inv[it]), (bf16)(oacc[md][it][3] * inv[it]) };
      int row = qbase + it * 16 + ln;               // token
      int col = h * HD + md * 16 + q * 4;           // 4 consecutive d
      *reinterpret_cast<bf16x4*>(&O[(size_t)(b * SEQ + row) * EMB + col]) = o4;
    }
}

// ---------------- launch ----------------
extern "C" void kernel_launch(void* const* d_in, const int* in_sizes, int n_in,
                              void* d_out, int out_size, void* d_ws, size_t ws_size,
                              hipStream_t stream)
{
  const float* x   = (const float*)d_in[0];
  const float* Wk  = (const float*)d_in[1];
  const float* Wq  = (const float*)d_in[2];
  const float* Wv  = (const float*)d_in[3];
  const float* Wo  = (const float*)d_in[4];
  const float* bo  = (const float*)d_in[5];
  const float* klg = (const float*)d_in[6];
  const float* klb = (const float*)d_in[7];
  const float* qlg = (const float*)d_in[8];
  const float* qlb = (const float*)d_in[9];
  float* out = (float*)d_out;

  char* ws = (char*)d_ws;
  const size_t OFF_XB  = 0;
  const size_t OFF_WB  = OFF_XB  + (size_t)BT * EMB * 2;
  const size_t OFF_KQV = OFF_WB  + (size_t)4 * EMB * EMB * 2;
  const size_t OFF_KN  = OFF_KQV + (size_t)BT * 3 * EMB * 2;
  const size_t OFF_QN  = OFF_KN  + (size_t)BT * EMB * 2;
  const size_t OFF_VT  = OFF_QN  + (size_t)BT * EMB * 2;
  const size_t OFF_END = OFF_VT  + (size_t)BT * EMB * 2;
  if (ws_size < OFF_END) return;

  bf16* xb   = (bf16*)(ws + OFF_XB);
  bf16* wb   = (bf16*)(ws + OFF_WB);
  bf16* kqv  = (bf16*)(ws + OFF_KQV);
  bf16* kn   = (bf16*)(ws + OFF_KN);
  bf16* qn   = (bf16*)(ws + OFF_QN);
  bf16* vt   = (bf16*)(ws + OFF_VT);
  bf16* ob   = (bf16*)(ws + OFF_KQV);    // alias: KQV dead after ln/v_trans

  cvt_f32_bf16<<<(BT * EMB / 4) / 256, 256, 0, stream>>>(x, xb, BT * EMB / 4);
  cvt_w4<<<(4 * EMB * EMB / 4) / 256, 256, 0, stream>>>(Wk, Wq, Wv, Wo, wb);

  gemm_bt<0><<<dim3(3 * EMB / 128, BT / 128), 256, 0, stream>>>(
      xb, wb, kqv, (float*)nullptr, (const float*)nullptr, BT, 3 * EMB, EMB);

  ln_kq<<<BT * HEADS / 4, 256, 0, stream>>>(kqv, kn, qn, klg, klb, qlg, qlb,
                                            QK_SCALE * LOG2E, QK_SCALE);
  v_trans<<<dim3(SEQ / 64, BATCH * HEADS), 256, 0, stream>>>(kqv + 2 * EMB, 3 * EMB, vt);

  attn<<<dim3(SEQ / 64, BATCH * HEADS), 128, 0, stream>>>(qn, kn, vt, ob);

  gemm_bt<1><<<dim3(EMB / 128, BT / 128), 256, 0, stream>>>(
      ob, wb + (size_t)3 * EMB * EMB, (bf16*)nullptr, out, bo, BT, EMB, EMB);
}

// Round 9
// 316.762 us; speedup vs baseline: 1.2547x; 1.1011x over previous
//
#include <hip/hip_runtime.h>
#include <hip/hip_bf16.h>
#include <cstdint>

#define EMB 1024
#define HEADS 16
#define HD 64
#define BATCH 4
#define SEQ 2048
#define BT (BATCH*SEQ)                 // 8192 tokens
#define LNEPS 1e-5f
#define QK_SCALE 0.17677669529663687f  // 1024^-0.25
#define LOG2E 1.4426950408889634f

typedef __bf16 bf16;
typedef __bf16 bf16x8 __attribute__((ext_vector_type(8)));
typedef __bf16 bf16x4 __attribute__((ext_vector_type(4)));
typedef float  f32x4  __attribute__((ext_vector_type(4)));
typedef short  s16x4  __attribute__((ext_vector_type(4)));

typedef const __attribute__((address_space(1))) void* gas_ptr;
typedef __attribute__((address_space(3))) void*       las_ptr;

__device__ __forceinline__ void gld_lds16(const void* g, void* l) {
  __builtin_amdgcn_global_load_lds((gas_ptr)g, (las_ptr)l, 16, 0, 0);
}

// PV matmul: 16x16x16 bf16 MFMA (C-layout of S^T == B-layout of this shape).
__device__ __forceinline__ f32x4 mfma_pv(bf16x4 a, bf16x4 b, f32x4 c) {
  return __builtin_amdgcn_mfma_f32_16x16x16bf16_1k(
      __builtin_bit_cast(s16x4, a), __builtin_bit_cast(s16x4, b), c, 0, 0, 0);
}

// ---------------- fp32 -> bf16 conversion ----------------
__global__ void cvt_f32_bf16(const float* __restrict__ src, bf16* __restrict__ dst, int n4) {
  int i = blockIdx.x * blockDim.x + threadIdx.x;
  if (i >= n4) return;
  float4 f = reinterpret_cast<const float4*>(src)[i];
  bf16x4 o = { (bf16)f.x, (bf16)f.y, (bf16)f.z, (bf16)f.w };
  reinterpret_cast<bf16x4*>(dst)[i] = o;
}

// 4 weight matrices (1024x1024 each) -> contiguous bf16 [4*1024][1024]
__global__ void cvt_w4(const float* __restrict__ w0, const float* __restrict__ w1,
                       const float* __restrict__ w2, const float* __restrict__ w3,
                       bf16* __restrict__ dst) {
  int i = blockIdx.x * blockDim.x + threadIdx.x;   // over 4*262144 float4s
  int sel = i >> 18;
  int j = i & 262143;
  const float* s = (sel == 0) ? w0 : (sel == 1) ? w1 : (sel == 2) ? w2 : w3;
  float4 f = reinterpret_cast<const float4*>(s)[j];
  bf16x4 o = { (bf16)f.x, (bf16)f.y, (bf16)f.z, (bf16)f.w };
  reinterpret_cast<bf16x4*>(dst)[i] = o;
}

// ---------------- m97-style GEMM: C[M][N] = A[M][K] * B[N][K]^T ----------------
template<int OUTF32>
__global__ __launch_bounds__(256, 2) void gemm_bt(
    const bf16* __restrict__ A, const bf16* __restrict__ Bm,
    bf16* __restrict__ Cb, float* __restrict__ Cf, const float* __restrict__ bias,
    int M, int N, int K)
{
  __shared__ __align__(16) bf16 As[128 * 32];
  __shared__ __align__(16) bf16 Bs[128 * 32];

  const int t    = threadIdx.x;
  const int lane = t & 63;
  const int wave = t >> 6;
  const int q    = lane >> 4;
  const int ln   = lane & 15;
  const int m0   = blockIdx.y * 128;
  const int n0   = blockIdx.x * 128;
  const int wm   = (wave >> 1) * 64;
  const int wn   = (wave & 1) * 64;

  const int r0 = t >> 2;
  const int c0 = (t & 3) << 3;

  f32x4 zero4 = {0.f, 0.f, 0.f, 0.f};
  f32x4 acc[4][4];
#pragma unroll
  for (int i = 0; i < 4; i++)
#pragma unroll
    for (int j = 0; j < 4; j++) acc[i][j] = zero4;

  for (int k0 = 0; k0 < K; k0 += 32) {
    __syncthreads();
    const bf16* ga = A  + (size_t)(m0 + r0) * K + k0 + c0;
    const bf16* gb = Bm + (size_t)(n0 + r0) * K + k0 + c0;
    gld_lds16(ga,                  &As[t * 8]);
    gld_lds16(ga + (size_t)64 * K, &As[t * 8 + 2048]);
    gld_lds16(gb,                  &Bs[t * 8]);
    gld_lds16(gb + (size_t)64 * K, &Bs[t * 8 + 2048]);
    __syncthreads();

    bf16x8 af[4], bfr[4];
#pragma unroll
    for (int mi = 0; mi < 4; mi++)
      af[mi] = *reinterpret_cast<const bf16x8*>(&As[(wm + mi * 16 + ln) * 32 + q * 8]);
#pragma unroll
    for (int ni = 0; ni < 4; ni++)
      bfr[ni] = *reinterpret_cast<const bf16x8*>(&Bs[(wn + ni * 16 + ln) * 32 + q * 8]);
#pragma unroll
    for (int mi = 0; mi < 4; mi++)
#pragma unroll
      for (int ni = 0; ni < 4; ni++)
        acc[mi][ni] = __builtin_amdgcn_mfma_f32_16x16x32_bf16(af[mi], bfr[ni], acc[mi][ni], 0, 0, 0);
  }

#pragma unroll
  for (int mi = 0; mi < 4; mi++) {
#pragma unroll
    for (int ni = 0; ni < 4; ni++) {
#pragma unroll
      for (int r = 0; r < 4; r++) {
        int row = m0 + wm + mi * 16 + q * 4 + r;
        int col = n0 + wn + ni * 16 + ln;
        float v = acc[mi][ni][r];
        if (OUTF32) Cf[(size_t)row * N + col] = v + bias[col];
        else        Cb[(size_t)row * N + col] = (bf16)v;
      }
    }
  }
}

// ---------------- per-head LayerNorm for K and Q, vectorized ----------------
// kqv: [8192][3072]; K at col 0, Q at col 1024. Outputs [bh][t][64].
// 8 lanes per row, bf16x8 loads/stores. kscale includes log2(e).
__global__ void ln_kq(const bf16* __restrict__ kqv,
                      bf16* __restrict__ kn, bf16* __restrict__ qn,
                      const float* __restrict__ kg, const float* __restrict__ kb,
                      const float* __restrict__ qg, const float* __restrict__ qb,
                      float kscale, float qscale)
{
  const int t = threadIdx.x;
  const int lr = t & 7;                       // lane within row
  const int row = blockIdx.x * 32 + (t >> 3); // row = tok*16 + h
  const int tok = row >> 4, h = row & 15;
  const size_t base = (size_t)tok * (3 * EMB) + h * HD + lr * 8;

  bf16x8 vk = *reinterpret_cast<const bf16x8*>(kqv + base);
  bf16x8 vq = *reinterpret_cast<const bf16x8*>(kqv + base + EMB);

  float fk[8], fq[8];
  float sk = 0.f, sq = 0.f, s2k = 0.f, s2q = 0.f;
#pragma unroll
  for (int e = 0; e < 8; e++) {
    fk[e] = (float)vk[e]; fq[e] = (float)vq[e];
    sk += fk[e]; sq += fq[e];
    s2k += fk[e] * fk[e]; s2q += fq[e] * fq[e];
  }
#pragma unroll
  for (int m = 1; m < 8; m <<= 1) {
    sk  += __shfl_xor(sk,  m, 64); sq  += __shfl_xor(sq,  m, 64);
    s2k += __shfl_xor(s2k, m, 64); s2q += __shfl_xor(s2q, m, 64);
  }
  float mk = sk * (1.f / 64.f), mq = sq * (1.f / 64.f);
  float rk = rsqrtf(s2k * (1.f / 64.f) - mk * mk + LNEPS) * kscale;
  float rq = rsqrtf(s2q * (1.f / 64.f) - mq * mq + LNEPS) * qscale;

  bf16x8 ok, oq;
#pragma unroll
  for (int e = 0; e < 8; e++) {
    float gk = kg[lr * 8 + e], bk2 = kb[lr * 8 + e];
    float gq = qg[lr * 8 + e], bq2 = qb[lr * 8 + e];
    ok[e] = (bf16)(((fk[e] - mk) * rk) * gk + bk2 * kscale);
    oq[e] = (bf16)(((fq[e] - mq) * rq) * gq + bq2 * qscale);
  }
  const int b = tok >> 11, tt = tok & 2047;
  const size_t o = ((size_t)(b * HEADS + h) * SEQ + tt) * HD + lr * 8;
  *reinterpret_cast<bf16x8*>(kn + o) = ok;
  *reinterpret_cast<bf16x8*>(qn + o) = oq;
}

// ---------------- V transpose: [t][3072] (V at col 2048) -> [bh][64 d][2048 t] ----------------
__global__ void v_trans(const bf16* __restrict__ in, int ldin, bf16* __restrict__ out)
{
  __shared__ __align__(16) bf16 tile[64][72];
  int bh = blockIdx.y, jt = blockIdx.x;
  int b = bh >> 4, h = bh & 15;
  int t = threadIdx.x;
#pragma unroll
  for (int p = 0; p < 2; p++) {
    int rowj = p * 32 + (t >> 3);
    int cold = (t & 7) << 3;
    bf16x8 v = *reinterpret_cast<const bf16x8*>(
        &in[(size_t)(b * SEQ + jt * 64 + rowj) * ldin + h * HD + cold]);
    *reinterpret_cast<bf16x8*>(&tile[rowj][cold]) = v;
  }
  __syncthreads();
#pragma unroll
  for (int p = 0; p < 2; p++) {
    int rowd = p * 32 + (t >> 3);
    int colj = (t & 7) << 3;
    bf16x8 v;
#pragma unroll
    for (int jj = 0; jj < 8; jj++) v[jj] = tile[colj + jj][rowd];
    *reinterpret_cast<bf16x8*>(&out[((size_t)bh * HD + rowd) * SEQ + jt * 64 + colj]) = v;
  }
}

// ---------------- flash attention (causal), S^T form, occupancy-max ----------------
// S^T = K*Q^T (16x16x32); C-layout == B-operand of 16x16x16 -> PV from registers.
// Grid 64 x 64 bh, 128 thr = 2 waves x 16 Q rows; j-tile 32; 8KB LDS -> 16 blocks/CU;
// launch_bounds(128,8) pins VGPR<=64 for 8 waves/SIMD. Shear (bx+by)&63 gives every
// CU's 16 blocks a uniform ~496 tile-steps (AP mod 64 sums exactly).
__global__ __launch_bounds__(128, 8) void attn(
    const bf16* __restrict__ Qn, const bf16* __restrict__ Kn, const bf16* __restrict__ Vt,
    bf16* __restrict__ O)
{
  __shared__ __align__(16) bf16 Ks[32 * 64];   // [j][d]
  __shared__ __align__(16) bf16 Vs[64 * 32];   // [d][j]

  const int bh = blockIdx.y;
  const int itile = ((int)blockIdx.x + (int)blockIdx.y) & 63;   // decorrelate from CU
  const int i0 = itile * 32;
  const int t = threadIdx.x, wave = t >> 6, lane = t & 63;
  const int q = lane >> 4, ln = lane & 15;
  const int qbase = i0 + wave * 16;

  // Q fragments (B-operand of S^T mfma): Q[i=qbase+ln][d=ks*32+q*8 ..+8]
  const bf16* qp = Qn + ((size_t)bh * SEQ + qbase + ln) * HD + q * 8;
  bf16x8 qf0 = *reinterpret_cast<const bf16x8*>(qp);
  bf16x8 qf1 = *reinterpret_cast<const bf16x8*>(qp + 32);

  float lrow = 0.f;
  f32x4 zero4 = {0.f, 0.f, 0.f, 0.f};
  f32x4 oacc[4];                          // [md] tiles of O^T[d][i]
#pragma unroll
  for (int md = 0; md < 4; md++) oacc[md] = zero4;

  const int nj = itile + 1;               // 32-j tiles covering 0..i0+31
  for (int jt = 0; jt < nj; jt++) {
    const int j0 = jt * 32;
    // stage K [32 j][64 d] (8-chunk rows, XOR^(row&7)) and V^T [64 d][32 j]
    // (4-chunk rows, XOR^(d&3)); 128 thr x 2 chunks each per tensor
#pragma unroll
    for (int s = 0; s < 2; s++) {
      int u = t * 8 + s * 1024;
      int krow = u >> 6;
      int kcs = ((u >> 3) & 7) ^ (krow & 7);
      gld_lds16(Kn + ((size_t)bh * SEQ + j0 + krow) * HD + kcs * 8, &Ks[u]);
      int vd = u >> 5;
      int vcs = ((u >> 3) & 3) ^ (vd & 3);
      gld_lds16(Vt + ((size_t)bh * HD + vd) * SEQ + j0 + vcs * 8, &Vs[u]);
    }
    __syncthreads();                       // tile visible

#pragma unroll
    for (int jb = 0; jb < 2; jb++) {
      if ((j0 + jb * 16) <= (qbase + 15)) {   // slab has unmasked elems for this wave
        const int rowj = jb * 16 + ln;
        bf16x8 kf0 = *reinterpret_cast<const bf16x8*>(&Ks[rowj * 64 + ((q)     ^ (rowj & 7)) * 8]);
        bf16x8 kf1 = *reinterpret_cast<const bf16x8*>(&Ks[rowj * 64 + ((4 + q) ^ (rowj & 7)) * 8]);
        f32x4 z = zero4;
        z = __builtin_amdgcn_mfma_f32_16x16x32_bf16(kf0, qf0, z, 0, 0, 0);
        z = __builtin_amdgcn_mfma_f32_16x16x32_bf16(kf1, qf1, z, 0, 0, 0);
        // z[r] = S^T[j = j0+jb*16+q*4+r][i = qbase+ln]
        if (j0 + jb * 16 + 15 > qbase) {      // partial slab: mask
#pragma unroll
          for (int r = 0; r < 4; r++) {
            int jj = j0 + jb * 16 + q * 4 + r;
            int ii = qbase + ln;
            if (jj > ii) z[r] = -1.0e30f;
          }
        }
        // fixed-max softmax (|s*log2e| <= 2.9 after per-head LN): p = 2^s
        float p0 = exp2f(z[0]), p1 = exp2f(z[1]), p2 = exp2f(z[2]), p3 = exp2f(z[3]);
        lrow += (p0 + p1) + (p2 + p3);
        bf16x4 pk = { (bf16)p0, (bf16)p1, (bf16)p2, (bf16)p3 };   // B-frag (k=j, n=i)

        // O^T += V^T * P^T for this 16-j slab
#pragma unroll
        for (int md = 0; md < 4; md++) {
          const int rowd = md * 16 + ln;
          const bf16* vp = &Vs[rowd * 32 + (((jb * 2 + (q >> 1)) ^ (rowd & 3)) * 8) + (q & 1) * 4];
          bf16x4 vf = *reinterpret_cast<const bf16x4*>(vp);
          oacc[md] = mfma_pv(vf, pk, oacc[md]);
        }
      }
    }
    __syncthreads();                       // all reads done before next stage
  }

  // epilogue: reduce l over the 4 quads holding each column i, normalize, store
  float s = lrow;
  s += __shfl_xor(s, 16, 64);
  s += __shfl_xor(s, 32, 64);
  const float inv = 1.f / s;
  const int b = bh >> 4, h = bh & 15;
  const int row = qbase + ln;
#pragma unroll
  for (int md = 0; md < 4; md++) {
    bf16x4 o4 = { (bf16)(oacc[md][0] * inv), (bf16)(oacc[md][1] * inv),
                  (bf16)(oacc[md][2] * inv), (bf16)(oacc[md][3] * inv) };
    int col = h * HD + md * 16 + q * 4;    // 4 consecutive d
    *reinterpret_cast<bf16x4*>(&O[(size_t)(b * SEQ + row) * EMB + col]) = o4;
  }
}

// ---------------- launch ----------------
extern "C" void kernel_launch(void* const* d_in, const int* in_sizes, int n_in,
                              void* d_out, int out_size, void* d_ws, size_t ws_size,
                              hipStream_t stream)
{
  const float* x   = (const float*)d_in[0];
  const float* Wk  = (const float*)d_in[1];
  const float* Wq  = (const float*)d_in[2];
  const float* Wv  = (const float*)d_in[3];
  const float* Wo  = (const float*)d_in[4];
  const float* bo  = (const float*)d_in[5];
  const float* klg = (const float*)d_in[6];
  const float* klb = (const float*)d_in[7];
  const float* qlg = (const float*)d_in[8];
  const float* qlb = (const float*)d_in[9];
  float* out = (float*)d_out;

  char* ws = (char*)d_ws;
  const size_t OFF_XB  = 0;
  const size_t OFF_WB  = OFF_XB  + (size_t)BT * EMB * 2;
  const size_t OFF_KQV = OFF_WB  + (size_t)4 * EMB * EMB * 2;
  const size_t OFF_KN  = OFF_KQV + (size_t)BT * 3 * EMB * 2;
  const size_t OFF_QN  = OFF_KN  + (size_t)BT * EMB * 2;
  const size_t OFF_VT  = OFF_QN  + (size_t)BT * EMB * 2;
  const size_t OFF_END = OFF_VT  + (size_t)BT * EMB * 2;
  if (ws_size < OFF_END) return;

  bf16* xb   = (bf16*)(ws + OFF_XB);
  bf16* wb   = (bf16*)(ws + OFF_WB);
  bf16* kqv  = (bf16*)(ws + OFF_KQV);
  bf16* kn   = (bf16*)(ws + OFF_KN);
  bf16* qn   = (bf16*)(ws + OFF_QN);
  bf16* vt   = (bf16*)(ws + OFF_VT);
  bf16* ob   = (bf16*)(ws + OFF_KQV);    // alias: KQV dead after ln/v_trans

  cvt_f32_bf16<<<(BT * EMB / 4) / 256, 256, 0, stream>>>(x, xb, BT * EMB / 4);
  cvt_w4<<<(4 * EMB * EMB / 4) / 256, 256, 0, stream>>>(Wk, Wq, Wv, Wo, wb);

  gemm_bt<0><<<dim3(3 * EMB / 128, BT / 128), 256, 0, stream>>>(
      xb, wb, kqv, (float*)nullptr, (const float*)nullptr, BT, 3 * EMB, EMB);

  ln_kq<<<BT * HEADS / 32, 256, 0, stream>>>(kqv, kn, qn, klg, klb, qlg, qlb,
                                             QK_SCALE * LOG2E, QK_SCALE);
  v_trans<<<dim3(SEQ / 64, BATCH * HEADS), 256, 0, stream>>>(kqv + 2 * EMB, 3 * EMB, vt);

  attn<<<dim3(64, BATCH * HEADS), 128, 0, stream>>>(qn, kn, vt, ob);

  gemm_bt<1><<<dim3(EMB / 128, BT / 128), 256, 0, stream>>>(
      ob, wb + (size_t)3 * EMB * EMB, (bf16*)nullptr, out, bo, BT, EMB, EMB);
}